// Round 5
// baseline (208.984 us; speedup 1.0000x reference)
//
#include <hip/hip_runtime.h>

// Problem: B=2, H=32, S=8192, D=128, T=512, fp32.
// out = (updated_k, updated_v) concatenated flat: each B*H*S*D = 67,108,864 floats.

#define S_LEN 8192
#define T_LEN 512
#define D_DIM 128
#define BH    64            // B*H
#define ELEMS_PER_TENSOR (BH * S_LEN * D_DIM)      // 67,108,864 floats
#define VECS_PER_BH      (S_LEN * (D_DIM / 4))     // 262,144 float4s per bh slice
#define NEW_VECS_PER_BH  (T_LEN * (D_DIM / 4))     // 16,384 float4s per bh slice

// Native clang vector type — __builtin_nontemporal_* requires this.
typedef float f4_t __attribute__((ext_vector_type(4)));

// --- single fused kernel -------------------------------------------------
// grid = (1024, 2, 2), block = 256.
//   blockIdx.z: 0 = K, 1 = V (1 read + 1 write stream per thread).
//   blockIdx.y: which half of the 64 bh slices.
//   blockIdx.x: 32 blocks per bh slice; each block streams a CONTIGUOUS
//               128 KiB chunk (256 seq rows) — memcpy-shaped access:
//               per iteration the block covers 4 KiB contiguous, walking
//               sequentially. No large-stride hops.
// The inverse position map for the block's 256 rows is built in LDS by
// scanning the 512 positions (2 per thread, L2-hot).
__global__ __launch_bounds__(256) void ssc_fused(
    const f4_t* __restrict__ ck, const f4_t* __restrict__ cv,
    const f4_t* __restrict__ nk, const f4_t* __restrict__ nv,
    const void* __restrict__ pos,
    f4_t* __restrict__ ok, f4_t* __restrict__ ov) {

    __shared__ int lmap[256];
    const int ltid = threadIdx.x;
    const int bh   = blockIdx.y * (BH / 2) + (blockIdx.x >> 5); // bh slice
    const int s0   = (blockIdx.x & 31) * 256;                   // first row of chunk

    lmap[ltid] = -1;
    __syncthreads();

    // positions may arrive as int32 or int64; detect by range-checking the
    // first two 8-byte reads (int32 read as int64 misparses element 1).
    {
        const long long* p64 = (const long long*)pos;
        const int*       p32 = (const int*)pos;
        long long a = p64[0], b = p64[1];
        bool is64 = (a >= 0) && (a < S_LEN) && (b >= 0) && (b < S_LEN) && (a != b);
        #pragma unroll
        for (int j = ltid; j < T_LEN; j += 256) {
            int p = is64 ? (int)p64[j] : p32[j];
            unsigned r = (unsigned)(p - s0);
            if (r < 256u) lmap[r] = j;
        }
    }
    __syncthreads();

    // pick tensor (grid-uniform)
    const f4_t* csrc = blockIdx.z ? cv : ck;
    const f4_t* nsrc = blockIdx.z ? nv : nk;
    f4_t*       odst = blockIdx.z ? ov : ok;

    const int chunkBase = bh * VECS_PER_BH + s0 * 32;  // first vec of chunk
    const f4_t* cbase = csrc + chunkBase + ltid;
    f4_t*       dbase = odst + chunkBase + ltid;
    const f4_t* nbase = nsrc + bh * NEW_VECS_PER_BH + (ltid & 31);
    const int   rlane = ltid >> 5;                     // row offset of this lane

    #pragma unroll 8
    for (int i = 0; i < 32; ++i) {
        const int t = lmap[i * 8 + rlane];
        f4_t v;
        if (t >= 0) v = nbase[t * 32];
        else        v = __builtin_nontemporal_load(cbase + i * 256);
        dbase[i * 256] = v;
    }
}

extern "C" void kernel_launch(void* const* d_in, const int* in_sizes, int n_in,
                              void* d_out, int out_size, void* d_ws, size_t ws_size,
                              hipStream_t stream) {
    const f4_t* ck = (const f4_t*)d_in[0];
    const f4_t* cv = (const f4_t*)d_in[1];
    const f4_t* nk = (const f4_t*)d_in[2];
    const f4_t* nv = (const f4_t*)d_in[3];
    const void* pos = d_in[4];

    float* out = (float*)d_out;
    f4_t* ok = (f4_t*)out;
    f4_t* ov = (f4_t*)(out + ELEMS_PER_TENSOR);

    ssc_fused<<<dim3(1024, 2, 2), 256, 0, stream>>>(ck, cv, nk, nv, pos, ok, ov);
}